// Round 10
// baseline (261.609 us; speedup 1.0000x reference)
//
#include <hip/hip_runtime.h>
#include <math.h>

// QuadraticAttention on MI355X — round 10: fuse Q/K/V GEMMs into one kernel.
// r9: gemm_qkv at its structural plateau (358 TF ~ m102's value for this
// shape; MfmaUtil 13%). The 3 slices share the A operand (x) — fusing gives
// 48 MFMA per 8 cp16 per iter (3x compute per barrier, 1.5x less staging per
// FLOP). 48 f32x4 accs (~192 regs, AGPR-able) — WRITE_SIZE is the spill
// tripwire. attn (r9), gemm_out, cvt unchanged.

typedef float  f32x4  __attribute__((ext_vector_type(4)));
typedef short  bf16x8 __attribute__((ext_vector_type(8)));
typedef float  vf4    __attribute__((ext_vector_type(4)));
typedef unsigned short u16x4 __attribute__((ext_vector_type(4)));

static __device__ __forceinline__ unsigned short f2bf(float f) {
    union { float f; unsigned int i; } c; c.f = f;
    unsigned int x = c.i;
    return (unsigned short)((x + 0x7fffu + ((x >> 16) & 1u)) >> 16);
}
static __device__ __forceinline__ f32x4 shfl_xor4(f32x4 v, int m) {
    f32x4 r;
    r[0] = __shfl_xor(v[0], m); r[1] = __shfl_xor(v[1], m);
    r[2] = __shfl_xor(v[2], m); r[3] = __shfl_xor(v[3], m);
    return r;
}
static __device__ __forceinline__ f32x4 rsq4(f32x4 v) {
    f32x4 r;
#pragma unroll
    for (int i = 0; i < 4; i++) r[i] = rsqrtf(v[i] * (1.0f / 64.0f) + 1.1920929e-07f);
    return r;
}
// async 16B/lane global -> LDS
static __device__ __forceinline__ void cp16(const unsigned short* g, unsigned short* l) {
    __builtin_amdgcn_global_load_lds(
        (const __attribute__((address_space(1))) unsigned int*)g,
        (__attribute__((address_space(3))) unsigned int*)l, 16, 0, 0);
}

#define FOR_M(X)  X(0) X(1) X(2) X(3)
#define FOR_MN(X) X(0,0) X(0,1) X(0,2) X(0,3) X(1,0) X(1,1) X(1,2) X(1,3) \
                  X(2,0) X(2,1) X(2,2) X(2,3) X(3,0) X(3,1) X(3,2) X(3,3)
#define FOR_MN2(X) X(0,0) X(0,1) X(0,2) X(0,3) X(1,0) X(1,1) X(1,2) X(1,3)

// ---------------------------------------------------------------------------
__global__ __launch_bounds__(256) void cvt_all(
    const float* __restrict__ x,  const float* __restrict__ Wq,
    const float* __restrict__ Wk, const float* __restrict__ Wv,
    const float* __restrict__ Wo,
    unsigned short* __restrict__ xb,  unsigned short* __restrict__ Wqb,
    unsigned short* __restrict__ Wkb, unsigned short* __restrict__ Wvb,
    unsigned short* __restrict__ Wob, int nx4, int nw4)
{
    int i = blockIdx.x * 256 + threadIdx.x;
    const float* s; unsigned short* d; int li;
    if (i < nx4) { s = x; d = xb; li = i; }
    else {
        int idx = i - nx4;
        int r = idx / nw4; li = idx - r * nw4;
        if (r >= 4) return;
        s = (r == 0) ? Wq : (r == 1) ? Wk : (r == 2) ? Wv : Wo;
        d = (r == 0) ? Wqb : (r == 1) ? Wkb : (r == 2) ? Wvb : Wob;
    }
    vf4 v = *(const vf4*)(s + (size_t)li * 4);
    u16x4 o;
#pragma unroll
    for (int j = 0; j < 4; j++) o[j] = f2bf(v[j]);
    *(u16x4*)(d + (size_t)li * 4) = o;
}

// ---------------------------------------------------------------------------
#define SS 136   // epilogue stage row stride (elems)

// ---------------------------------------------------------------------------
// Fused QKV GEMM: one block computes q,k,v 128x128 tiles for (m0,n0).
// K-loop stages A once + 3 W tiles (cp16), 48 MFMA/wave/iter.
// Epilogues: q,k -> bias+rmsnorm+rope (x0.125 folded scale); v -> transposed.
// ---------------------------------------------------------------------------
__global__ __launch_bounds__(256) void gemm_qkv(
    const unsigned short* __restrict__ xb,
    const unsigned short* __restrict__ Wqb,
    const unsigned short* __restrict__ Wkb,
    const unsigned short* __restrict__ Wvb,
    const float* __restrict__ bqf, const float* __restrict__ bkf, const float* __restrict__ bvf,
    const float* __restrict__ nwp,
    unsigned short* __restrict__ qb, unsigned short* __restrict__ kb,
    unsigned short* __restrict__ vT, int M)
{
    const int K = 1024;
    __shared__ unsigned short smem[128 * SS];   // 34816 B; staging (32KB) + stage alias
    unsigned short* As  = smem;                 // [128][32] each, 4096 elems
    unsigned short* Wqs = smem + 4096;
    unsigned short* Wks = smem + 8192;
    unsigned short* Wvs = smem + 12288;
    const int tid = threadIdx.x;
    const int n0 = blockIdx.x * 128;
    const int m0 = blockIdx.y * 128;
    const int lane = tid & 63, wid = tid >> 6;
    const int wy = wid >> 1, wx = wid & 1;
    const int l15 = lane & 15, quad = lane >> 4;
    const int r16 = lane >> 2;
    const int c8  = (lane & 3) * 8;

#define Q_DECL_ACC(mi,ni) f32x4 cq##mi##ni = {0.f,0.f,0.f,0.f}; \
                          f32x4 ck##mi##ni = {0.f,0.f,0.f,0.f}; \
                          f32x4 cv##mi##ni = {0.f,0.f,0.f,0.f};
    FOR_MN(Q_DECL_ACC)

    for (int kt = 0; kt < K; kt += 32) {
        __syncthreads();
#pragma unroll
        for (int j = 0; j < 2; j++) {
            const int ch = wid * 2 + j;               // 0..7, 16 rows each
            const int row = ch * 16 + r16;
            cp16(xb  + (size_t)(m0 + row) * K + kt + c8, &As [ch * 512]);
            cp16(Wqb + (size_t)(n0 + row) * K + kt + c8, &Wqs[ch * 512]);
            cp16(Wkb + (size_t)(n0 + row) * K + kt + c8, &Wks[ch * 512]);
            cp16(Wvb + (size_t)(n0 + row) * K + kt + c8, &Wvs[ch * 512]);
        }
        __syncthreads();
#define Q_DECL_A(mi) bf16x8 a##mi = *(const bf16x8*)&As[(wy * 64 + (mi) * 16 + l15) * 32 + quad * 8];
        FOR_M(Q_DECL_A)
        {
#define QB_DECL(ni) bf16x8 b##ni = *(const bf16x8*)&Wqs[(wx * 64 + (ni) * 16 + l15) * 32 + quad * 8];
            FOR_M(QB_DECL)
#define Q_MFMA_Q(mi,ni) cq##mi##ni = __builtin_amdgcn_mfma_f32_16x16x32_bf16(a##mi, b##ni, cq##mi##ni, 0, 0, 0);
            FOR_MN(Q_MFMA_Q)
        }
        {
#define KB_DECL(ni) bf16x8 b##ni = *(const bf16x8*)&Wks[(wx * 64 + (ni) * 16 + l15) * 32 + quad * 8];
            FOR_M(KB_DECL)
#define Q_MFMA_K(mi,ni) ck##mi##ni = __builtin_amdgcn_mfma_f32_16x16x32_bf16(a##mi, b##ni, ck##mi##ni, 0, 0, 0);
            FOR_MN(Q_MFMA_K)
        }
        {
#define VB_DECL(ni) bf16x8 b##ni = *(const bf16x8*)&Wvs[(wx * 64 + (ni) * 16 + l15) * 32 + quad * 8];
            FOR_M(VB_DECL)
#define Q_MFMA_V(mi,ni) cv##mi##ni = __builtin_amdgcn_mfma_f32_16x16x32_bf16(a##mi, b##ni, cv##mi##ni, 0, 0, 0);
            FOR_MN(Q_MFMA_V)
        }
    }
    __syncthreads();   // MFMA LDS reads done; smem reused as epilogue stage

    const float nww0 = nwp[l15],      nww1 = nwp[16 + l15];
    const float nww2 = nwp[32 + l15], nww3 = nwp[48 + l15];
    const float lf0 = expf(-(float)l15 * 0.28782313662425572f);          // ln(1e4)/32
    const float lf1 = expf(-(float)(l15 + 16) * 0.28782313662425572f);

    // ---- q / k epilogues: bias + rmsnorm + rope(+0.125 scale) ----
#define EPI_ROPE_ONE(P,mi,ni,NW,CS,SN) { \
            float vn = P##mi##ni[r] * s2v[r] * NW; \
            float pt = __shfl_xor(vn, 1); \
            float rot = (lane & 1) ? pt : -pt; \
            smem[mrow * SS + wx * 64 + (ni) * 16 + l15] = f2bf((vn * (CS) + rot * (SN)) * 0.125f); }
#define EPI_ROPE_MI(P,mi) { f32x4 s2v = s2_##mi; \
            _Pragma("unroll") \
            for (int r = 0; r < 4; r++) { \
                const int mrow = wy * 64 + (mi) * 16 + quad * 4 + r; \
                const float t = (float)((m0 + mrow) & 2047); \
                const float a0 = t * lf0, a1 = t * lf1; \
                const float cs0 = cosf(a0), sn0 = sinf(a0); \
                const float cs1 = cosf(a1), sn1 = sinf(a1); \
                EPI_ROPE_ONE(P,mi,0,nww0,cs0,sn0) EPI_ROPE_ONE(P,mi,1,nww1,cs1,sn1) \
                EPI_ROPE_ONE(P,mi,2,nww2,cs0,sn0) EPI_ROPE_ONE(P,mi,3,nww3,cs1,sn1) } }

#define EPI_QK(P, BIASPTR, DSTPTR) { \
        const float bs0 = BIASPTR[n0 + wx * 64 + l15]; \
        const float bs1 = BIASPTR[n0 + wx * 64 + 16 + l15]; \
        const float bs2 = BIASPTR[n0 + wx * 64 + 32 + l15]; \
        const float bs3 = BIASPTR[n0 + wx * 64 + 48 + l15]; \
        P##00 += bs0; P##01 += bs1; P##02 += bs2; P##03 += bs3; \
        P##10 += bs0; P##11 += bs1; P##12 += bs2; P##13 += bs3; \
        P##20 += bs0; P##21 += bs1; P##22 += bs2; P##23 += bs3; \
        P##30 += bs0; P##31 += bs1; P##32 += bs2; P##33 += bs3; \
        f32x4 s2_0 = P##00*P##00 + P##01*P##01 + P##02*P##02 + P##03*P##03; \
        f32x4 s2_1 = P##10*P##10 + P##11*P##11 + P##12*P##12 + P##13*P##13; \
        f32x4 s2_2 = P##20*P##20 + P##21*P##21 + P##22*P##22 + P##23*P##23; \
        f32x4 s2_3 = P##30*P##30 + P##31*P##31 + P##32*P##32 + P##33*P##33; \
        s2_0 = s2_0 + shfl_xor4(s2_0,1); s2_0 = s2_0 + shfl_xor4(s2_0,2); \
        s2_0 = s2_0 + shfl_xor4(s2_0,4); s2_0 = s2_0 + shfl_xor4(s2_0,8); s2_0 = rsq4(s2_0); \
        s2_1 = s2_1 + shfl_xor4(s2_1,1); s2_1 = s2_1 + shfl_xor4(s2_1,2); \
        s2_1 = s2_1 + shfl_xor4(s2_1,4); s2_1 = s2_1 + shfl_xor4(s2_1,8); s2_1 = rsq4(s2_1); \
        s2_2 = s2_2 + shfl_xor4(s2_2,1); s2_2 = s2_2 + shfl_xor4(s2_2,2); \
        s2_2 = s2_2 + shfl_xor4(s2_2,4); s2_2 = s2_2 + shfl_xor4(s2_2,8); s2_2 = rsq4(s2_2); \
        s2_3 = s2_3 + shfl_xor4(s2_3,1); s2_3 = s2_3 + shfl_xor4(s2_3,2); \
        s2_3 = s2_3 + shfl_xor4(s2_3,4); s2_3 = s2_3 + shfl_xor4(s2_3,8); s2_3 = rsq4(s2_3); \
        EPI_ROPE_MI(P,0) EPI_ROPE_MI(P,1) EPI_ROPE_MI(P,2) EPI_ROPE_MI(P,3) \
        __syncthreads(); \
        _Pragma("unroll") \
        for (int it = 0; it < 8; it++) { \
            const int linear = tid + it * 256; \
            const int row = linear >> 4, cb = linear & 15; \
            *(bf16x8*)(DSTPTR + (size_t)(m0 + row) * 1024 + n0 + cb * 8) = \
                *(const bf16x8*)&smem[row * SS + cb * 8]; \
        } \
        __syncthreads(); }

    EPI_QK(cq, bqf, qb)
    EPI_QK(ck, bkf, kb)

    // ---- v epilogue: bias + transposed per-head store ----
    {
        const float bs0 = bvf[n0 + wx * 64 + l15];
        const float bs1 = bvf[n0 + wx * 64 + 16 + l15];
        const float bs2 = bvf[n0 + wx * 64 + 32 + l15];
        const float bs3 = bvf[n0 + wx * 64 + 48 + l15];
        cv00 += bs0; cv01 += bs1; cv02 += bs2; cv03 += bs3;
        cv10 += bs0; cv11 += bs1; cv12 += bs2; cv13 += bs3;
        cv20 += bs0; cv21 += bs1; cv22 += bs2; cv23 += bs3;
        cv30 += bs0; cv31 += bs1; cv32 += bs2; cv33 += bs3;
#define EPI_VST(mi,ni) { _Pragma("unroll") \
            for (int r = 0; r < 4; r++) { \
                const int mrow = wy * 64 + (mi) * 16 + quad * 4 + r; \
                smem[(wx * 64 + (ni) * 16 + l15) * SS + mrow] = f2bf(cv##mi##ni[r]); } }
        FOR_MN(EPI_VST)
        __syncthreads();
        const int b = m0 >> 11, tok0 = m0 & 2047;
#pragma unroll
        for (int it = 0; it < 8; it++) {
            const int linear = tid + it * 256;
            const int rowd = linear >> 4, cb = linear & 15;
            const int head_g = (n0 >> 6) + (rowd >> 6);
            const int d = rowd & 63;
            *(bf16x8*)(vT + (((size_t)b * 16 + head_g) * 64 + d) * 2048 + tok0 + cb * 8) =
                *(const bf16x8*)&smem[rowd * SS + cb * 8];
        }
    }
}

// ---------------------------------------------------------------------------
#define G_DECL_ACC(mi,ni) f32x4 c##mi##ni = {0.f, 0.f, 0.f, 0.f};
#define G_DECL_A(mi) bf16x8 a##mi = *(const bf16x8*)&As[(wy * 64 + (mi) * 16 + l15) * 32 + quad * 8];
#define G_DECL_B(ni) bf16x8 b##ni = *(const bf16x8*)&Ws[(wx * 64 + (ni) * 16 + l15) * 32 + quad * 8];
#define G_MFMA(mi,ni) c##mi##ni = __builtin_amdgcn_mfma_f32_16x16x32_bf16(a##mi, b##ni, c##mi##ni, 0, 0, 0);

__global__ __launch_bounds__(256) void gemm_out(
    const unsigned short* __restrict__ zb,
    const unsigned short* __restrict__ Wob,
    const float* __restrict__ x, float* __restrict__ out, int M)
{
    const int K = 1024;
    __shared__ unsigned short As[4096];
    __shared__ unsigned short Ws[4096];
    const int tid = threadIdx.x;
    const int n0 = blockIdx.x * 128;
    const int m0 = blockIdx.y * 128;
    const int lane = tid & 63, wid = tid >> 6;
    const int wy = wid >> 1, wx = wid & 1;
    const int l15 = lane & 15, quad = lane >> 4;
    const int r16 = lane >> 2;
    const int c8  = (lane & 3) * 8;

    FOR_MN(G_DECL_ACC)

    for (int kt = 0; kt < K; kt += 32) {
        __syncthreads();
#pragma unroll
        for (int j = 0; j < 2; j++) {
            const int ch = wid * 2 + j;
            const int row = ch * 16 + r16;
            cp16(zb + (size_t)(m0 + row) * K + kt + c8, &As[ch * 512]);
            cp16(Wob + (size_t)(n0 + row) * K + kt + c8, &Ws[ch * 512]);
        }
        __syncthreads();
        FOR_M(G_DECL_A)
        FOR_M(G_DECL_B)
        FOR_MN(G_MFMA)
    }

#define G_OUTST(mi,ni) { _Pragma("unroll") \
        for (int r = 0; r < 4; r++) { \
            const int m = m0 + wy * 64 + (mi) * 16 + quad * 4 + r; \
            const int n = n0 + wx * 64 + (ni) * 16 + l15; \
            out[(size_t)m * 1024 + n] = c##mi##ni[r] + x[(size_t)m * 1024 + n]; } }
    FOR_MN(G_OUTST)
}

// ---------------------------------------------------------------------------
// Causal quadratic attention (r9 structure, unchanged).
// ---------------------------------------------------------------------------
__global__ __launch_bounds__(256) void attn_mfma(
    const unsigned short* __restrict__ qb, const unsigned short* __restrict__ kb,
    const unsigned short* __restrict__ vT, unsigned short* __restrict__ zb)
{
    __shared__ unsigned short Qs[128 * 72];
    __shared__ unsigned short Ks[64 * 72];
    __shared__ unsigned short Vs[64 * 72];   // rows = d, cols = k-token
    __shared__ unsigned short Pm[128 * 72];
    const int tid = threadIdx.x;
    const int qt = 15 - blockIdx.x;           // big tiles first
    const int bh = blockIdx.y;
    const int b = bh >> 4, h = bh & 15;
    const int lane = tid & 63, wq = tid >> 6;
    const int l15 = lane & 15, quad = lane >> 4;
    const size_t tokbase = (size_t)b * 2048;
    const int q0 = qt * 128;

#pragma unroll
    for (int j = 0; j < 4; j++) {
        const int u = tid + j * 256;
        const int row = u >> 3, seg = (u & 7) * 8;
        bf16x8 v = *(const bf16x8*)(qb + (tokbase + q0 + row) * 1024 + h * 64 + seg);
        *(bf16x8*)&Qs[row * 72 + seg] = v;
    }
    __syncthreads();
    const bf16x8 aq00 = *(const bf16x8*)&Qs[(wq * 32 + l15) * 72 + quad * 8];
    const bf16x8 aq01 = *(const bf16x8*)&Qs[(wq * 32 + l15) * 72 + 32 + quad * 8];
    const bf16x8 aq10 = *(const bf16x8*)&Qs[(wq * 32 + 16 + l15) * 72 + quad * 8];
    const bf16x8 aq11 = *(const bf16x8*)&Qs[(wq * 32 + 16 + l15) * 72 + 32 + quad * 8];

    const int kr = tid >> 3;                  // 0..31
    const int sg = (tid & 7) * 8;

    bf16x8 pk0, pk1, pv0, pv1;
#define A_GLB(KT) { \
        pk0 = *(const bf16x8*)(kb + (tokbase + (KT) * 64 + kr) * 1024 + h * 64 + sg); \
        pk1 = *(const bf16x8*)(kb + (tokbase + (KT) * 64 + kr + 32) * 1024 + h * 64 + sg); \
        pv0 = *(const bf16x8*)(vT + ((size_t)bh * 64 + kr) * 2048 + (KT) * 64 + sg); \
        pv1 = *(const bf16x8*)(vT + ((size_t)bh * 64 + kr + 32) * 2048 + (KT) * 64 + sg); }

#define A_DECL_Z(mi,n) f32x4 z_##mi##n = {0.f, 0.f, 0.f, 0.f};
    FOR_MN2(A_DECL_Z)

    const int nkt = 2 * qt + 2;
    A_GLB(0)
    for (int kt = 0; kt < nkt; kt++) {
        __syncthreads();
        *(bf16x8*)&Ks[kr * 72 + sg] = pk0;
        *(bf16x8*)&Ks[(kr + 32) * 72 + sg] = pk1;
        *(bf16x8*)&Vs[kr * 72 + sg] = pv0;
        *(bf16x8*)&Vs[(kr + 32) * 72 + sg] = pv1;
        __syncthreads();
        if (kt + 1 < nkt) A_GLB(kt + 1)

#define A_DECL_S(mi,n) f32x4 s_##mi##n = {0.f, 0.f, 0.f, 0.f};
        FOR_MN2(A_DECL_S)
#define A_QKH(KS, AQ0, AQ1) { \
        bf16x8 b0 = *(const bf16x8*)&Ks[(l15) * 72 + (KS) * 32 + quad * 8]; \
        bf16x8 b1 = *(const bf16x8*)&Ks[(16 + l15) * 72 + (KS) * 32 + quad * 8]; \
        bf16x8 b2 = *(const bf16x8*)&Ks[(32 + l15) * 72 + (KS) * 32 + quad * 8]; \
        bf16x8 b3 = *(const bf16x8*)&Ks[(48 + l15) * 72 + (KS) * 32 + quad * 8]; \
        s_00 = __builtin_amdgcn_mfma_f32_16x16x32_bf16(AQ0, b0, s_00, 0, 0, 0); \
        s_01 = __builtin_amdgcn_mfma_f32_16x16x32_bf16(AQ0, b1, s_01, 0, 0, 0); \
        s_02 = __builtin_amdgcn_mfma_f32_16x16x32_bf16(AQ0, b2, s_02, 0, 0, 0); \
        s_03 = __builtin_amdgcn_mfma_f32_16x16x32_bf16(AQ0, b3, s_03, 0, 0, 0); \
        s_10 = __builtin_amdgcn_mfma_f32_16x16x32_bf16(AQ1, b0, s_10, 0, 0, 0); \
        s_11 = __builtin_amdgcn_mfma_f32_16x16x32_bf16(AQ1, b1, s_11, 0, 0, 0); \
        s_12 = __builtin_amdgcn_mfma_f32_16x16x32_bf16(AQ1, b2, s_12, 0, 0, 0); \
        s_13 = __builtin_amdgcn_mfma_f32_16x16x32_bf16(AQ1, b3, s_13, 0, 0, 0); }
        A_QKH(0, aq00, aq10)
        A_QKH(1, aq01, aq11)

        const bool needmask = (kt >= 2 * qt);
#define A_PSTORE(mi,n) { \
        f32x4 p4 = s_##mi##n * s_##mi##n; \
        if (needmask) { _Pragma("unroll") \
            for (int r = 0; r < 4; r++) \
                if (kt * 64 + (n) * 16 + l15 > q0 + wq * 32 + (mi) * 16 + quad * 4 + r) p4[r] = 0.f; } \
        _Pragma("unroll") \
        for (int r = 0; r < 4; r++) \
            Pm[(wq * 32 + (mi) * 16 + quad * 4 + r) * 72 + (n) * 16 + l15] = f2bf(p4[r]); }
        FOR_MN2(A_PSTORE)

#define A_PVH(KS) { \
        bf16x8 ap0 = *(const bf16x8*)&Pm[(wq * 32 + l15) * 72 + (KS) * 32 + quad * 8]; \
        bf16x8 ap1 = *(const bf16x8*)&Pm[(wq * 32 + 16 + l15) * 72 + (KS) * 32 + quad * 8]; \
        bf16x8 u0 = *(const bf16x8*)&Vs[(l15) * 72 + (KS) * 32 + quad * 8]; \
        bf16x8 u1 = *(const bf16x8*)&Vs[(16 + l15) * 72 + (KS) * 32 + quad * 8]; \
        bf16x8 u2 = *(const bf16x8*)&Vs[(32 + l15) * 72 + (KS) * 32 + quad * 8]; \
        bf16x8 u3 = *(const bf16x8*)&Vs[(48 + l15) * 72 + (KS) * 32 + quad * 8]; \
        z_00 = __builtin_amdgcn_mfma_f32_16x16x32_bf16(ap0, u0, z_00, 0, 0, 0); \
        z_01 = __builtin_amdgcn_mfma_f32_16x16x32_bf16(ap0, u1, z_01, 0, 0, 0); \
        z_02 = __builtin_amdgcn_mfma_f32_16x16x32_bf16(ap0, u2, z_02, 0, 0, 0); \
        z_03 = __builtin_amdgcn_mfma_f32_16x16x32_bf16(ap0, u3, z_03, 0, 0, 0); \
        z_10 = __builtin_amdgcn_mfma_f32_16x16x32_bf16(ap1, u0, z_10, 0, 0, 0); \
        z_11 = __builtin_amdgcn_mfma_f32_16x16x32_bf16(ap1, u1, z_11, 0, 0, 0); \
        z_12 = __builtin_amdgcn_mfma_f32_16x16x32_bf16(ap1, u2, z_12, 0, 0, 0); \
        z_13 = __builtin_amdgcn_mfma_f32_16x16x32_bf16(ap1, u3, z_13, 0, 0, 0); }
        A_PVH(0)
        A_PVH(1)
    }

#define A_ZST(mi,n) { _Pragma("unroll") \
        for (int r = 0; r < 4; r++) \
            Pm[(wq * 32 + (mi) * 16 + quad * 4 + r) * 72 + (n) * 16 + l15] = f2bf(z_##mi##n[r]); }
    FOR_MN2(A_ZST)
#pragma unroll
    for (int it = 0; it < 4; it++) {
        const int linear = it * 64 + lane;
        const int row = linear >> 3, cb = linear & 7;
        *(bf16x8*)(zb + (tokbase + q0 + wq * 32 + row) * 1024 + h * 64 + cb * 8) =
            *(const bf16x8*)&Pm[(wq * 32 + row) * 72 + cb * 8];
    }
}

// ---------------------------------------------------------------------------
extern "C" void kernel_launch(void* const* d_in, const int* in_sizes, int n_in,
                              void* d_out, int out_size, void* d_ws, size_t ws_size,
                              hipStream_t stream)
{
    const float* x  = (const float*)d_in[0];
    const float* Wq = (const float*)d_in[1];
    const float* bq = (const float*)d_in[2];
    const float* Wk = (const float*)d_in[3];
    const float* bk = (const float*)d_in[4];
    const float* Wv = (const float*)d_in[5];
    const float* bv = (const float*)d_in[6];
    const float* Wo = (const float*)d_in[7];
    const float* nw = (const float*)d_in[8];
    float* out = (float*)d_out;

    const int D = 1024;
    const int M = in_sizes[0] / D;   // B*S = 4096

    unsigned short* xbb = (unsigned short*)d_ws;         // M*D
    unsigned short* Wqb = xbb + (size_t)M * D;           // D*D
    unsigned short* Wkb = Wqb + (size_t)D * D;
    unsigned short* Wvb = Wkb + (size_t)D * D;
    unsigned short* Wob = Wvb + (size_t)D * D;
    unsigned short* qbw = Wob + (size_t)D * D;           // M*D
    unsigned short* kbw = qbw + (size_t)M * D;
    unsigned short* vTw = kbw + (size_t)M * D;
    unsigned short* zbw = vTw + (size_t)M * D;

    const int nx4 = M * D / 4, nw4 = D * D / 4;
    const int ncvt = nx4 + 4 * nw4;
    cvt_all<<<(ncvt + 255) / 256, 256, 0, stream>>>(
        x, Wq, Wk, Wv, Wo, xbb, Wqb, Wkb, Wvb, Wob, nx4, nw4);

    gemm_qkv<<<dim3(D / 128, M / 128), 256, 0, stream>>>(
        xbb, Wqb, Wkb, Wvb, bq, bk, bv, nw, qbw, kbw, vTw, M);

    attn_mfma<<<dim3(16, (M / 2048) * 16), 256, 0, stream>>>(qbw, kbw, vTw, zbw);

    gemm_out<<<dim3(D / 128, M / 128), 256, 0, stream>>>(zbw, Wob, x, out, M);
}

// Round 11
// 235.011 us; speedup vs baseline: 1.1132x; 1.1132x over previous
//
#include <hip/hip_runtime.h>
#include <math.h>

// QuadraticAttention on MI355X — round 11: fused QKV, occupancy fixed.
// r10: fusion halved FETCH (69->37MB, no spill) but 256thr x 256blk = 1
// wave/SIMD -> zero overlap -> 93us. Now 512-thread blocks (8 waves),
// 128x128 tile, wave = 32m x 64n x {q,k,v} (24 f32x4 accs ~160 VGPR,
// 2-3 waves/SIMD HW cap), grid 256 = 1 blk/CU = 2 waves/SIMD.
// 24 MFMA : 4 cp16 per wave-iter. attn (r9), gemm_out, cvt unchanged.

typedef float  f32x4  __attribute__((ext_vector_type(4)));
typedef short  bf16x8 __attribute__((ext_vector_type(8)));
typedef float  vf4    __attribute__((ext_vector_type(4)));
typedef unsigned short u16x4 __attribute__((ext_vector_type(4)));

static __device__ __forceinline__ unsigned short f2bf(float f) {
    union { float f; unsigned int i; } c; c.f = f;
    unsigned int x = c.i;
    return (unsigned short)((x + 0x7fffu + ((x >> 16) & 1u)) >> 16);
}
static __device__ __forceinline__ f32x4 shfl_xor4(f32x4 v, int m) {
    f32x4 r;
    r[0] = __shfl_xor(v[0], m); r[1] = __shfl_xor(v[1], m);
    r[2] = __shfl_xor(v[2], m); r[3] = __shfl_xor(v[3], m);
    return r;
}
static __device__ __forceinline__ f32x4 rsq4(f32x4 v) {
    f32x4 r;
#pragma unroll
    for (int i = 0; i < 4; i++) r[i] = rsqrtf(v[i] * (1.0f / 64.0f) + 1.1920929e-07f);
    return r;
}
// async 16B/lane global -> LDS
static __device__ __forceinline__ void cp16(const unsigned short* g, unsigned short* l) {
    __builtin_amdgcn_global_load_lds(
        (const __attribute__((address_space(1))) unsigned int*)g,
        (__attribute__((address_space(3))) unsigned int*)l, 16, 0, 0);
}

#define FOR_2(X)  X(0) X(1)
#define FOR_M(X)  X(0) X(1) X(2) X(3)
#define FOR_MN(X) X(0,0) X(0,1) X(0,2) X(0,3) X(1,0) X(1,1) X(1,2) X(1,3) \
                  X(2,0) X(2,1) X(2,2) X(2,3) X(3,0) X(3,1) X(3,2) X(3,3)
#define FOR_MN2(X) X(0,0) X(0,1) X(0,2) X(0,3) X(1,0) X(1,1) X(1,2) X(1,3)

// ---------------------------------------------------------------------------
__global__ __launch_bounds__(256) void cvt_all(
    const float* __restrict__ x,  const float* __restrict__ Wq,
    const float* __restrict__ Wk, const float* __restrict__ Wv,
    const float* __restrict__ Wo,
    unsigned short* __restrict__ xb,  unsigned short* __restrict__ Wqb,
    unsigned short* __restrict__ Wkb, unsigned short* __restrict__ Wvb,
    unsigned short* __restrict__ Wob, int nx4, int nw4)
{
    int i = blockIdx.x * 256 + threadIdx.x;
    const float* s; unsigned short* d; int li;
    if (i < nx4) { s = x; d = xb; li = i; }
    else {
        int idx = i - nx4;
        int r = idx / nw4; li = idx - r * nw4;
        if (r >= 4) return;
        s = (r == 0) ? Wq : (r == 1) ? Wk : (r == 2) ? Wv : Wo;
        d = (r == 0) ? Wqb : (r == 1) ? Wkb : (r == 2) ? Wvb : Wob;
    }
    vf4 v = *(const vf4*)(s + (size_t)li * 4);
    u16x4 o;
#pragma unroll
    for (int j = 0; j < 4; j++) o[j] = f2bf(v[j]);
    *(u16x4*)(d + (size_t)li * 4) = o;
}

// ---------------------------------------------------------------------------
#define SS 136   // epilogue stage row stride (elems)

// ---------------------------------------------------------------------------
// Fused QKV GEMM, 512 threads / 8 waves. Block computes q,k,v 128x128 tiles
// for (m0,n0). Wave (wy 0..3, wx 0..1) owns 32m x 64n of each output.
// K-loop: stage A + Wq + Wk + Wv ([128][32] each, cp16), 24 MFMA/wave.
// ---------------------------------------------------------------------------
__global__ __launch_bounds__(512) void gemm_qkv(
    const unsigned short* __restrict__ xb,
    const unsigned short* __restrict__ Wqb,
    const unsigned short* __restrict__ Wkb,
    const unsigned short* __restrict__ Wvb,
    const float* __restrict__ bqf, const float* __restrict__ bkf, const float* __restrict__ bvf,
    const float* __restrict__ nwp,
    unsigned short* __restrict__ qb, unsigned short* __restrict__ kb,
    unsigned short* __restrict__ vT, int M)
{
    const int K = 1024;
    __shared__ unsigned short smem[128 * SS];   // 34816 B; staging 32KB aliased
    unsigned short* As  = smem;                 // [128][32] each
    unsigned short* Wqs = smem + 4096;
    unsigned short* Wks = smem + 8192;
    unsigned short* Wvs = smem + 12288;
    const int tid = threadIdx.x;
    const int n0 = blockIdx.x * 128;
    const int m0 = blockIdx.y * 128;
    const int lane = tid & 63, wid = tid >> 6;   // wid 0..7
    const int wy = wid >> 1, wx = wid & 1;       // wy 0..3 (32 m-rows), wx 0..1 (64 n-cols)
    const int l15 = lane & 15, quad = lane >> 4;
    const int r16 = lane >> 2;
    const int c8  = (lane & 3) * 8;

#define Q_DECL_ACC(mi,ni) f32x4 cq##mi##ni = {0.f,0.f,0.f,0.f}; \
                          f32x4 ck##mi##ni = {0.f,0.f,0.f,0.f}; \
                          f32x4 cv##mi##ni = {0.f,0.f,0.f,0.f};
    FOR_MN2(Q_DECL_ACC)

    for (int kt = 0; kt < K; kt += 32) {
        __syncthreads();
#pragma unroll
        for (int j = 0; j < 4; j++) {
            const int ch = wid * 4 + j;          // 0..31 chunks of 16 rows
            const int mat = ch >> 3;             // 0:A 1:Wq 2:Wk 3:Wv
            const int row = (ch & 7) * 16 + r16;
            const unsigned short* g =
                (mat == 0) ? xb  + (size_t)(m0 + row) * K + kt + c8 :
                (mat == 1) ? Wqb + (size_t)(n0 + row) * K + kt + c8 :
                (mat == 2) ? Wkb + (size_t)(n0 + row) * K + kt + c8 :
                             Wvb + (size_t)(n0 + row) * K + kt + c8;
            cp16(g, &smem[ch * 512]);
        }
        __syncthreads();
#define Q_DECL_A(mi) bf16x8 a##mi = *(const bf16x8*)&As[(wy * 32 + (mi) * 16 + l15) * 32 + quad * 8];
        FOR_2(Q_DECL_A)
        {
#define QB_DECL(ni) bf16x8 b##ni = *(const bf16x8*)&Wqs[(wx * 64 + (ni) * 16 + l15) * 32 + quad * 8];
            FOR_M(QB_DECL)
#define Q_MFMA_Q(mi,ni) cq##mi##ni = __builtin_amdgcn_mfma_f32_16x16x32_bf16(a##mi, b##ni, cq##mi##ni, 0, 0, 0);
            FOR_MN2(Q_MFMA_Q)
        }
        {
#define KB_DECL(ni) bf16x8 b##ni = *(const bf16x8*)&Wks[(wx * 64 + (ni) * 16 + l15) * 32 + quad * 8];
            FOR_M(KB_DECL)
#define Q_MFMA_K(mi,ni) ck##mi##ni = __builtin_amdgcn_mfma_f32_16x16x32_bf16(a##mi, b##ni, ck##mi##ni, 0, 0, 0);
            FOR_MN2(Q_MFMA_K)
        }
        {
#define VB_DECL(ni) bf16x8 b##ni = *(const bf16x8*)&Wvs[(wx * 64 + (ni) * 16 + l15) * 32 + quad * 8];
            FOR_M(VB_DECL)
#define Q_MFMA_V(mi,ni) cv##mi##ni = __builtin_amdgcn_mfma_f32_16x16x32_bf16(a##mi, b##ni, cv##mi##ni, 0, 0, 0);
            FOR_MN2(Q_MFMA_V)
        }
    }
    __syncthreads();   // MFMA LDS reads done; smem reused as epilogue stage

    const float nww0 = nwp[l15],      nww1 = nwp[16 + l15];
    const float nww2 = nwp[32 + l15], nww3 = nwp[48 + l15];
    const float lf0 = expf(-(float)l15 * 0.28782313662425572f);          // ln(1e4)/32
    const float lf1 = expf(-(float)(l15 + 16) * 0.28782313662425572f);

#define EPI_ROPE_ONE(P,mi,ni,NW,CS,SN) { \
            float vn = P##mi##ni[r] * s2v[r] * NW; \
            float pt = __shfl_xor(vn, 1); \
            float rot = (lane & 1) ? pt : -pt; \
            smem[mrow * SS + wx * 64 + (ni) * 16 + l15] = f2bf((vn * (CS) + rot * (SN)) * 0.125f); }
#define EPI_ROPE_MI(P,mi) { f32x4 s2v = s2_##mi; \
            _Pragma("unroll") \
            for (int r = 0; r < 4; r++) { \
                const int mrow = wy * 32 + (mi) * 16 + quad * 4 + r; \
                const float t = (float)((m0 + mrow) & 2047); \
                const float a0 = t * lf0, a1 = t * lf1; \
                const float cs0 = cosf(a0), sn0 = sinf(a0); \
                const float cs1 = cosf(a1), sn1 = sinf(a1); \
                EPI_ROPE_ONE(P,mi,0,nww0,cs0,sn0) EPI_ROPE_ONE(P,mi,1,nww1,cs1,sn1) \
                EPI_ROPE_ONE(P,mi,2,nww2,cs0,sn0) EPI_ROPE_ONE(P,mi,3,nww3,cs1,sn1) } }

#define EPI_QK(P, BIASPTR, DSTPTR) { \
        const float bs0 = BIASPTR[n0 + wx * 64 + l15]; \
        const float bs1 = BIASPTR[n0 + wx * 64 + 16 + l15]; \
        const float bs2 = BIASPTR[n0 + wx * 64 + 32 + l15]; \
        const float bs3 = BIASPTR[n0 + wx * 64 + 48 + l15]; \
        P##00 += bs0; P##01 += bs1; P##02 += bs2; P##03 += bs3; \
        P##10 += bs0; P##11 += bs1; P##12 += bs2; P##13 += bs3; \
        f32x4 s2_0 = P##00*P##00 + P##01*P##01 + P##02*P##02 + P##03*P##03; \
        f32x4 s2_1 = P##10*P##10 + P##11*P##11 + P##12*P##12 + P##13*P##13; \
        s2_0 = s2_0 + shfl_xor4(s2_0,1); s2_0 = s2_0 + shfl_xor4(s2_0,2); \
        s2_0 = s2_0 + shfl_xor4(s2_0,4); s2_0 = s2_0 + shfl_xor4(s2_0,8); s2_0 = rsq4(s2_0); \
        s2_1 = s2_1 + shfl_xor4(s2_1,1); s2_1 = s2_1 + shfl_xor4(s2_1,2); \
        s2_1 = s2_1 + shfl_xor4(s2_1,4); s2_1 = s2_1 + shfl_xor4(s2_1,8); s2_1 = rsq4(s2_1); \
        EPI_ROPE_MI(P,0) EPI_ROPE_MI(P,1) \
        __syncthreads(); \
        _Pragma("unroll") \
        for (int it = 0; it < 4; it++) { \
            const int linear = tid + it * 512; \
            const int row = linear >> 4, cb = linear & 15; \
            *(bf16x8*)(DSTPTR + (size_t)(m0 + row) * 1024 + n0 + cb * 8) = \
                *(const bf16x8*)&smem[row * SS + cb * 8]; \
        } \
        __syncthreads(); }

    EPI_QK(cq, bqf, qb)
    EPI_QK(ck, bkf, kb)

    // ---- v epilogue: bias + transposed per-head store ----
    {
        const float bs0 = bvf[n0 + wx * 64 + l15];
        const float bs1 = bvf[n0 + wx * 64 + 16 + l15];
        const float bs2 = bvf[n0 + wx * 64 + 32 + l15];
        const float bs3 = bvf[n0 + wx * 64 + 48 + l15];
        cv00 += bs0; cv01 += bs1; cv02 += bs2; cv03 += bs3;
        cv10 += bs0; cv11 += bs1; cv12 += bs2; cv13 += bs3;
#define EPI_VST(mi,ni) { _Pragma("unroll") \
            for (int r = 0; r < 4; r++) { \
                const int mrow = wy * 32 + (mi) * 16 + quad * 4 + r; \
                smem[(wx * 64 + (ni) * 16 + l15) * SS + mrow] = f2bf(cv##mi##ni[r]); } }
        FOR_MN2(EPI_VST)
        __syncthreads();
        const int b = m0 >> 11, tok0 = m0 & 2047;
#pragma unroll
        for (int it = 0; it < 4; it++) {
            const int linear = tid + it * 512;
            const int rowd = linear >> 4, cb = linear & 15;
            const int head_g = (n0 >> 6) + (rowd >> 6);
            const int d = rowd & 63;
            *(bf16x8*)(vT + (((size_t)b * 16 + head_g) * 64 + d) * 2048 + tok0 + cb * 8) =
                *(const bf16x8*)&smem[rowd * SS + cb * 8];
        }
    }
}

// ---------------------------------------------------------------------------
#define G_DECL_ACC(mi,ni) f32x4 c##mi##ni = {0.f, 0.f, 0.f, 0.f};
#define G_DECL_A(mi) bf16x8 a##mi = *(const bf16x8*)&As[(wy * 64 + (mi) * 16 + l15) * 32 + quad * 8];
#define G_DECL_B(ni) bf16x8 b##ni = *(const bf16x8*)&Ws[(wx * 64 + (ni) * 16 + l15) * 32 + quad * 8];
#define G_MFMA(mi,ni) c##mi##ni = __builtin_amdgcn_mfma_f32_16x16x32_bf16(a##mi, b##ni, c##mi##ni, 0, 0, 0);

__global__ __launch_bounds__(256) void gemm_out(
    const unsigned short* __restrict__ zb,
    const unsigned short* __restrict__ Wob,
    const float* __restrict__ x, float* __restrict__ out, int M)
{
    const int K = 1024;
    __shared__ unsigned short As[4096];
    __shared__ unsigned short Ws[4096];
    const int tid = threadIdx.x;
    const int n0 = blockIdx.x * 128;
    const int m0 = blockIdx.y * 128;
    const int lane = tid & 63, wid = tid >> 6;
    const int wy = wid >> 1, wx = wid & 1;
    const int l15 = lane & 15, quad = lane >> 4;
    const int r16 = lane >> 2;
    const int c8  = (lane & 3) * 8;

    FOR_MN(G_DECL_ACC)

    for (int kt = 0; kt < K; kt += 32) {
        __syncthreads();
#pragma unroll
        for (int j = 0; j < 2; j++) {
            const int ch = wid * 2 + j;
            const int row = ch * 16 + r16;
            cp16(zb + (size_t)(m0 + row) * K + kt + c8, &As[ch * 512]);
            cp16(Wob + (size_t)(n0 + row) * K + kt + c8, &Ws[ch * 512]);
        }
        __syncthreads();
        FOR_M(G_DECL_A)
        FOR_M(G_DECL_B)
        FOR_MN(G_MFMA)
    }

#define G_OUTST(mi,ni) { _Pragma("unroll") \
        for (int r = 0; r < 4; r++) { \
            const int m = m0 + wy * 64 + (mi) * 16 + quad * 4 + r; \
            const int n = n0 + wx * 64 + (ni) * 16 + l15; \
            out[(size_t)m * 1024 + n] = c##mi##ni[r] + x[(size_t)m * 1024 + n]; } }
    FOR_MN(G_OUTST)
}

// ---------------------------------------------------------------------------
// Causal quadratic attention (r9 structure, unchanged).
// ---------------------------------------------------------------------------
__global__ __launch_bounds__(256) void attn_mfma(
    const unsigned short* __restrict__ qb, const unsigned short* __restrict__ kb,
    const unsigned short* __restrict__ vT, unsigned short* __restrict__ zb)
{
    __shared__ unsigned short Qs[128 * 72];
    __shared__ unsigned short Ks[64 * 72];
    __shared__ unsigned short Vs[64 * 72];   // rows = d, cols = k-token
    __shared__ unsigned short Pm[128 * 72];
    const int tid = threadIdx.x;
    const int qt = 15 - blockIdx.x;           // big tiles first
    const int bh = blockIdx.y;
    const int b = bh >> 4, h = bh & 15;
    const int lane = tid & 63, wq = tid >> 6;
    const int l15 = lane & 15, quad = lane >> 4;
    const size_t tokbase = (size_t)b * 2048;
    const int q0 = qt * 128;

#pragma unroll
    for (int j = 0; j < 4; j++) {
        const int u = tid + j * 256;
        const int row = u >> 3, seg = (u & 7) * 8;
        bf16x8 v = *(const bf16x8*)(qb + (tokbase + q0 + row) * 1024 + h * 64 + seg);
        *(bf16x8*)&Qs[row * 72 + seg] = v;
    }
    __syncthreads();
    const bf16x8 aq00 = *(const bf16x8*)&Qs[(wq * 32 + l15) * 72 + quad * 8];
    const bf16x8 aq01 = *(const bf16x8*)&Qs[(wq * 32 + l15) * 72 + 32 + quad * 8];
    const bf16x8 aq10 = *(const bf16x8*)&Qs[(wq * 32 + 16 + l15) * 72 + quad * 8];
    const bf16x8 aq11 = *(const bf16x8*)&Qs[(wq * 32 + 16 + l15) * 72 + 32 + quad * 8];

    const int kr = tid >> 3;                  // 0..31
    const int sg = (tid & 7) * 8;

    bf16x8 pk0, pk1, pv0, pv1;
#define A_GLB(KT) { \
        pk0 = *(const bf16x8*)(kb + (tokbase + (KT) * 64 + kr) * 1024 + h * 64 + sg); \
        pk1 = *(const bf16x8*)(kb + (tokbase + (KT) * 64 + kr + 32) * 1024 + h * 64 + sg); \
        pv0 = *(const bf16x8*)(vT + ((size_t)bh * 64 + kr) * 2048 + (KT) * 64 + sg); \
        pv1 = *(const bf16x8*)(vT + ((size_t)bh * 64 + kr + 32) * 2048 + (KT) * 64 + sg); }

#define A_DECL_Z(mi,n) f32x4 z_##mi##n = {0.f, 0.f, 0.f, 0.f};
    FOR_MN2(A_DECL_Z)

    const int nkt = 2 * qt + 2;
    A_GLB(0)
    for (int kt = 0; kt < nkt; kt++) {
        __syncthreads();
        *(bf16x8*)&Ks[kr * 72 + sg] = pk0;
        *(bf16x8*)&Ks[(kr + 32) * 72 + sg] = pk1;
        *(bf16x8*)&Vs[kr * 72 + sg] = pv0;
        *(bf16x8*)&Vs[(kr + 32) * 72 + sg] = pv1;
        __syncthreads();
        if (kt + 1 < nkt) A_GLB(kt + 1)

#define A_DECL_S(mi,n) f32x4 s_##mi##n = {0.f, 0.f, 0.f, 0.f};
        FOR_MN2(A_DECL_S)
#define A_QKH(KS, AQ0, AQ1) { \
        bf16x8 b0 = *(const bf16x8*)&Ks[(l15) * 72 + (KS) * 32 + quad * 8]; \
        bf16x8 b1 = *(const bf16x8*)&Ks[(16 + l15) * 72 + (KS) * 32 + quad * 8]; \
        bf16x8 b2 = *(const bf16x8*)&Ks[(32 + l15) * 72 + (KS) * 32 + quad * 8]; \
        bf16x8 b3 = *(const bf16x8*)&Ks[(48 + l15) * 72 + (KS) * 32 + quad * 8]; \
        s_00 = __builtin_amdgcn_mfma_f32_16x16x32_bf16(AQ0, b0, s_00, 0, 0, 0); \
        s_01 = __builtin_amdgcn_mfma_f32_16x16x32_bf16(AQ0, b1, s_01, 0, 0, 0); \
        s_02 = __builtin_amdgcn_mfma_f32_16x16x32_bf16(AQ0, b2, s_02, 0, 0, 0); \
        s_03 = __builtin_amdgcn_mfma_f32_16x16x32_bf16(AQ0, b3, s_03, 0, 0, 0); \
        s_10 = __builtin_amdgcn_mfma_f32_16x16x32_bf16(AQ1, b0, s_10, 0, 0, 0); \
        s_11 = __builtin_amdgcn_mfma_f32_16x16x32_bf16(AQ1, b1, s_11, 0, 0, 0); \
        s_12 = __builtin_amdgcn_mfma_f32_16x16x32_bf16(AQ1, b2, s_12, 0, 0, 0); \
        s_13 = __builtin_amdgcn_mfma_f32_16x16x32_bf16(AQ1, b3, s_13, 0, 0, 0); }
        A_QKH(0, aq00, aq10)
        A_QKH(1, aq01, aq11)

        const bool needmask = (kt >= 2 * qt);
#define A_PSTORE(mi,n) { \
        f32x4 p4 = s_##mi##n * s_##mi##n; \
        if (needmask) { _Pragma("unroll") \
            for (int r = 0; r < 4; r++) \
                if (kt * 64 + (n) * 16 + l15 > q0 + wq * 32 + (mi) * 16 + quad * 4 + r) p4[r] = 0.f; } \
        _Pragma("unroll") \
        for (int r = 0; r < 4; r++) \
            Pm[(wq * 32 + (mi) * 16 + quad * 4 + r) * 72 + (n) * 16 + l15] = f2bf(p4[r]); }
        FOR_MN2(A_PSTORE)

#define A_PVH(KS) { \
        bf16x8 ap0 = *(const bf16x8*)&Pm[(wq * 32 + l15) * 72 + (KS) * 32 + quad * 8]; \
        bf16x8 ap1 = *(const bf16x8*)&Pm[(wq * 32 + 16 + l15) * 72 + (KS) * 32 + quad * 8]; \
        bf16x8 u0 = *(const bf16x8*)&Vs[(l15) * 72 + (KS) * 32 + quad * 8]; \
        bf16x8 u1 = *(const bf16x8*)&Vs[(16 + l15) * 72 + (KS) * 32 + quad * 8]; \
        bf16x8 u2 = *(const bf16x8*)&Vs[(32 + l15) * 72 + (KS) * 32 + quad * 8]; \
        bf16x8 u3 = *(const bf16x8*)&Vs[(48 + l15) * 72 + (KS) * 32 + quad * 8]; \
        z_00 = __builtin_amdgcn_mfma_f32_16x16x32_bf16(ap0, u0, z_00, 0, 0, 0); \
        z_01 = __builtin_amdgcn_mfma_f32_16x16x32_bf16(ap0, u1, z_01, 0, 0, 0); \
        z_02 = __builtin_amdgcn_mfma_f32_16x16x32_bf16(ap0, u2, z_02, 0, 0, 0); \
        z_03 = __builtin_amdgcn_mfma_f32_16x16x32_bf16(ap0, u3, z_03, 0, 0, 0); \
        z_10 = __builtin_amdgcn_mfma_f32_16x16x32_bf16(ap1, u0, z_10, 0, 0, 0); \
        z_11 = __builtin_amdgcn_mfma_f32_16x16x32_bf16(ap1, u1, z_11, 0, 0, 0); \
        z_12 = __builtin_amdgcn_mfma_f32_16x16x32_bf16(ap1, u2, z_12, 0, 0, 0); \
        z_13 = __builtin_amdgcn_mfma_f32_16x16x32_bf16(ap1, u3, z_13, 0, 0, 0); }
        A_PVH(0)
        A_PVH(1)
    }

#define A_ZST(mi,n) { _Pragma("unroll") \
        for (int r = 0; r < 4; r++) \
            Pm[(wq * 32 + (mi) * 16 + quad * 4 + r) * 72 + (n) * 16 + l15] = f2bf(z_##mi##n[r]); }
    FOR_MN2(A_ZST)
#pragma unroll
    for (int it = 0; it < 4; it++) {
        const int linear = it * 64 + lane;
        const int row = linear >> 3, cb = linear & 7;
        *(bf16x8*)(zb + (tokbase + q0 + wq * 32 + row) * 1024 + h * 64 + cb * 8) =
            *(const bf16x8*)&Pm[(wq * 32 + row) * 72 + cb * 8];
    }
}

// ---------------------------------------------------------------------------
extern "C" void kernel_launch(void* const* d_in, const int* in_sizes, int n_in,
                              void* d_out, int out_size, void* d_ws, size_t ws_size,
                              hipStream_t stream)
{
    const float* x  = (const float*)d_in[0];
    const float* Wq = (const float*)d_in[1];
    const float* bq = (const float*)d_in[2];
    const float* Wk = (const float*)d_in[3];
    const float* bk = (const float*)d_in[4];
    const float* Wv = (const float*)d_in[5];
    const float* bv = (const float*)d_in[6];
    const float* Wo = (const float*)d_in[7];
    const float* nw = (const float*)d_in[8];
    float* out = (float*)d_out;

    const int D = 1024;
    const int M = in_sizes[0] / D;   // B*S = 4096

    unsigned short* xbb = (unsigned short*)d_ws;         // M*D
    unsigned short* Wqb = xbb + (size_t)M * D;           // D*D
    unsigned short* Wkb = Wqb + (size_t)D * D;
    unsigned short* Wvb = Wkb + (size_t)D * D;
    unsigned short* Wob = Wvb + (size_t)D * D;
    unsigned short* qbw = Wob + (size_t)D * D;           // M*D
    unsigned short* kbw = qbw + (size_t)M * D;
    unsigned short* vTw = kbw + (size_t)M * D;
    unsigned short* zbw = vTw + (size_t)M * D;

    const int nx4 = M * D / 4, nw4 = D * D / 4;
    const int ncvt = nx4 + 4 * nw4;
    cvt_all<<<(ncvt + 255) / 256, 256, 0, stream>>>(
        x, Wq, Wk, Wv, Wo, xbb, Wqb, Wkb, Wvb, Wob, nx4, nw4);

    gemm_qkv<<<dim3(D / 128, M / 128), 512, 0, stream>>>(
        xbb, Wqb, Wkb, Wvb, bq, bk, bv, nw, qbw, kbw, vTw, M);

    attn_mfma<<<dim3(16, (M / 2048) * 16), 256, 0, stream>>>(qbw, kbw, vTw, zbw);

    gemm_out<<<dim3(D / 128, M / 128), 256, 0, stream>>>(zbw, Wob, x, out, M);
}